// Round 1
// baseline (452.496 us; speedup 1.0000x reference)
//
#include <hip/hip_runtime.h>
#include <hip/hip_bf16.h>

#define B_ 256
#define T_ 512
#define I_ 128
#define H_ 256

// 2*log2(e): weights/bias/xw are pre-scaled by this so the scan accumulator
// holds s = 2*log2e*z and tanh(z) = 1 - 2/(1 + 2^s) needs NO multiply before
// v_exp (v_exp_f32 IS exp2).
#define SC 2.885390081777927f

typedef __bf16 bf16x8 __attribute__((ext_vector_type(8)));
typedef float  f32x4  __attribute__((ext_vector_type(4)));
typedef unsigned short u16;
typedef unsigned int   u32;

union U16x8Cast { uint4 v; bf16x8 b; };

__device__ inline u16 f2b(float f) {           // fp32 -> bf16 bits (RNE)
    union { __bf16 h; u16 u; } c; c.h = (__bf16)f; return c.u;
}
__device__ inline bf16x8 pack8s(float4 lo, float4 hi, float s) {
    bf16x8 f;
    f[0]=(__bf16)(lo.x*s); f[1]=(__bf16)(lo.y*s); f[2]=(__bf16)(lo.z*s); f[3]=(__bf16)(lo.w*s);
    f[4]=(__bf16)(hi.x*s); f[5]=(__bf16)(hi.y*s); f[6]=(__bf16)(hi.z*s); f[7]=(__bf16)(hi.w*s);
    return f;
}
__device__ inline uint2 pack4(float a, float b, float c, float d) {
    uint2 p;
    p.x = (u32)f2b(a) | ((u32)f2b(b) << 16);
    p.y = (u32)f2b(c) | ((u32)f2b(d) << 16);
    return p;
}
__device__ inline f32x4 b4_to_f32x4(uint2 u) {
    f32x4 r;
    r[0] = __uint_as_float(u.x << 16);
    r[1] = __uint_as_float(u.x & 0xFFFF0000u);
    r[2] = __uint_as_float(u.y << 16);
    r[3] = __uint_as_float(u.y & 0xFFFF0000u);
    return r;
}
// tanh(z) with PRE-SCALED input s = 2*log2e*z:
//   tanh(z) = 1 - 2/(1+e^{2z}) = 1 - 2/(1 + 2^s)
// v_exp_f32 computes 2^x directly; v_rcp (±1 ulp) instead of precise-div.
// s -> +inf: e=inf, r=0, result 1; s -> -inf: e=0, r=1, result -1. No NaN.
__device__ inline float tanh_pre(float s) {
    float e;
    asm("v_exp_f32 %0, %1" : "=v"(e) : "v"(s));
    float d = 1.f + e;
    float r;
    asm("v_rcp_f32 %0, %1" : "=v"(r) : "v"(d));
    return fmaf(-2.f, r, 1.f);
}

// LDS-drain-only workgroup barrier: does NOT wait vmcnt, so global
// prefetch loads stay in flight across the barrier.
#define WG_BARRIER() asm volatile("s_waitcnt lgkmcnt(0)\n\ts_barrier" ::: "memory")

// =====================================================================
// Kernel 1 (MFMA GEMM): xw[t][b][n] = SC * (x[bT+t,:]*W_ih[n,:] + bias)
// 128-row m-tile, LDS-staged coalesced bf16 stores to [t][b][n].
// Only change vs prev: W_ih frags and bias are pre-scaled by SC.
// =====================================================================
#define LDST 264
__global__ __launch_bounds__(256, 2) void xw_gemm_mfma(const float* __restrict__ x,
                                                       const float* __restrict__ W_ih,
                                                       const float* __restrict__ b_ih,
                                                       const float* __restrict__ b_hh,
                                                       u16* __restrict__ xw) {
    __shared__ u16 tile[64 * LDST];

    const int tid  = (int)threadIdx.x;
    const int wave = tid >> 6;
    const int lane = tid & 63;
    const int q    = lane >> 4;
    const int ml   = lane & 15;
    const int m0   = (int)blockIdx.x * 128;
    const int b    = m0 >> 9;
    const int t0   = m0 & 511;
    const int n0   = wave * 64;

    bf16x8 wA[4][4];
#pragma unroll
    for (int tau = 0; tau < 4; ++tau) {
        const float* wr = W_ih + (size_t)(n0 + tau * 16 + ml) * I_;
#pragma unroll
        for (int kap = 0; kap < 4; ++kap) {
            const int k0 = kap * 32 + q * 8;
            wA[tau][kap] = pack8s(*(const float4*)(wr + k0), *(const float4*)(wr + k0 + 4), SC);
        }
    }

    f32x4 acc[8][4];
#pragma unroll
    for (int mt = 0; mt < 8; ++mt)
#pragma unroll
        for (int tau = 0; tau < 4; ++tau) acc[mt][tau] = (f32x4)0.f;

#pragma unroll
    for (int kap = 0; kap < 4; ++kap) {
        bf16x8 xB[8];
#pragma unroll
        for (int mt = 0; mt < 8; ++mt) {
            const float* xr = x + (size_t)(m0 + mt * 16 + ml) * I_ + kap * 32 + q * 8;
            xB[mt] = pack8s(*(const float4*)xr, *(const float4*)(xr + 4), 1.f);
        }
#pragma unroll
        for (int mt = 0; mt < 8; ++mt)
#pragma unroll
            for (int tau = 0; tau < 4; ++tau)
                acc[mt][tau] = __builtin_amdgcn_mfma_f32_16x16x32_bf16(
                    wA[tau][kap], xB[mt], acc[mt][tau], 0, 0, 0);
    }

    float4 bias4[4];
#pragma unroll
    for (int tau = 0; tau < 4; ++tau) {
        const int n = n0 + tau * 16 + q * 4;
        float4 bi = *(const float4*)(b_ih + n);
        float4 bh = *(const float4*)(b_hh + n);
        bias4[tau] = make_float4((bi.x + bh.x) * SC, (bi.y + bh.y) * SC,
                                 (bi.z + bh.z) * SC, (bi.w + bh.w) * SC);
    }

#pragma unroll
    for (int p = 0; p < 2; ++p) {
        if (p) __syncthreads();
#pragma unroll
        for (int mt = 0; mt < 4; ++mt) {
            const int row = mt * 16 + ml;
            const int mg  = p * 4 + mt;
#pragma unroll
            for (int tau = 0; tau < 4; ++tau) {
                uint2 pk = pack4(acc[mg][tau][0] + bias4[tau].x,
                                 acc[mg][tau][1] + bias4[tau].y,
                                 acc[mg][tau][2] + bias4[tau].z,
                                 acc[mg][tau][3] + bias4[tau].w);
                *(uint2*)(tile + row * LDST + n0 + tau * 16 + q * 4) = pk;
            }
        }
        __syncthreads();
#pragma unroll
        for (int s = 0; s < 4; ++s) {
            const int rr = s * 16 + (tid >> 4);
            const int c  = tid & 15;
            const uint4* srcp = (const uint4*)(tile + rr * LDST);
            uint4* dstp = (uint4*)(xw + ((size_t)(t0 + p * 64 + rr) * B_ + b) * H_);
            uint4 v0 = srcp[c];
            uint4 v1 = srcp[c + 16];
            dstp[c] = v0;
            dstp[c + 16] = v1;
        }
    }
}

// =====================================================================
// Kernel 2 (MFMA scan) — restructured from 8 waves to 4 waves per group.
// Rationale: per step, EVERY wave re-reads the full h (8 KB) from LDS as
// B-frags; with 8 waves that is 64 KB reads/step = ~800 cyc of LDS port
// (the dominant cost at 1480 cyc/step). Per-SIMD VALU (tanh/pack) and
// per-pipe MFMA are invariant in wave count (total work fixed, 4 SIMDs
// fixed), so halving waves halves ONLY the LDS term.
//   16 WGs x 256 thr (4 waves, 1/SIMD). Wave owns 64 H-rows (4 tau tiles).
// h ping-pongs in LDS in B-frag order (linear b128, 2-way max = free).
// tanh uses the SC-prescaled accumulator (raw v_exp, no pre-multiply).
// =====================================================================
__global__ __launch_bounds__(256, 1) void rnn_scan_mfma(const u16* __restrict__ xw,
                                                        const float* __restrict__ W_hh,
                                                        const float* __restrict__ fc_w,
                                                        const float* __restrict__ fc_b,
                                                        float* __restrict__ out) {
    __shared__ __attribute__((aligned(16))) u16 hbuf[2][4096];  // 2 x 8 KB
    __shared__ float red[4][16];

    const int tid  = (int)threadIdx.x;
    const int wave = tid >> 6;          // 0..3
    const int lane = tid & 63;
    const int q    = lane >> 4;
    const int m    = lane & 15;
    const int b0   = (int)blockIdx.x * 16;

    // W_hh A-frags (pre-scaled by SC): lane holds
    //   SC * W_hh[n = wave*64+tau*16+m][k = kap*32+q*8+0..7]
    bf16x8 wf[4][8];
#pragma unroll
    for (int tau = 0; tau < 4; ++tau) {
        const float* wr = W_hh + (size_t)(wave * 64 + tau * 16 + m) * H_;
#pragma unroll
        for (int kap = 0; kap < 8; ++kap) {
            const int k0 = kap * 32 + q * 8;
            wf[tau][kap] = pack8s(*(const float4*)(wr + k0), *(const float4*)(wr + k0 + 4), SC);
        }
    }

    // LDS write indices (u16 units) for C -> B-frag relayout
    int widx[4];
#pragma unroll
    for (int tau = 0; tau < 4; ++tau) {
        const int nbw = wave * 64 + tau * 16 + q * 4;
        widx[tau] = (nbw >> 5) * 512 + (((nbw >> 3) & 3) * 16 + m) * 8 + (nbw & 7);
    }

    {   // zero h buffer 0 (8 KB = 512 uint4, 256 threads -> 2 each)
        uint4* p = (uint4*)&hbuf[0][0];
        const uint4 z = {0u, 0u, 0u, 0u};
        p[tid] = z;
        p[tid + 256] = z;
    }
    WG_BARRIER();

    // xw ([t][b][n]): lane reads 4 x uint2 per step (16 outputs/lane).
    const u16* xwp = xw + (size_t)(b0 + m) * H_ + (wave * 64 + q * 4);
    const size_t tstride = (size_t)B_ * H_;

    uint2 pfA[4], pfB[4];                              // alternating, never copied
#pragma unroll
    for (int tau = 0; tau < 4; ++tau) pfA[tau] = *(const uint2*)(xwp + tau * 16);
#pragma unroll
    for (int tau = 0; tau < 4; ++tau) pfB[tau] = *(const uint2*)(xwp + tstride + tau * 16);

    int cur = 0;
    f32x4 acc[4];
    for (int tt = 0; tt < T_ / 2; ++tt) {
        // ---------- step A: t = 2*tt (even, never last) ----------
        {
            const int t = 2 * tt;
#pragma unroll
            for (int tau = 0; tau < 4; ++tau) acc[tau] = b4_to_f32x4(pfA[tau]);
            if (t + 2 < T_) {                          // reload pfA for t+2
                const u16* pt = xwp + (size_t)(t + 2) * tstride;
#pragma unroll
                for (int tau = 0; tau < 4; ++tau) pfA[tau] = *(const uint2*)(pt + tau * 16);
            }
            const uint4* hb = (const uint4*)&hbuf[cur][0];
#pragma unroll
            for (int kap = 0; kap < 8; ++kap) {
                U16x8Cast c; c.v = hb[kap * 64 + lane];
#pragma unroll
                for (int tau = 0; tau < 4; ++tau)
                    acc[tau] = __builtin_amdgcn_mfma_f32_16x16x32_bf16(wf[tau][kap], c.b, acc[tau], 0, 0, 0);
            }
            u16* wb = &hbuf[cur ^ 1][0];
#pragma unroll
            for (int tau = 0; tau < 4; ++tau) {
                uint2 pk = pack4(tanh_pre(acc[tau][0]), tanh_pre(acc[tau][1]),
                                 tanh_pre(acc[tau][2]), tanh_pre(acc[tau][3]));
                *(uint2*)(wb + widx[tau]) = pk;
            }
            WG_BARRIER();
            cur ^= 1;
        }
        // ---------- step B: t = 2*tt+1 (t = T_-1 on the last iter) ----------
        {
            const int t = 2 * tt + 1;
#pragma unroll
            for (int tau = 0; tau < 4; ++tau) acc[tau] = b4_to_f32x4(pfB[tau]);
            if (t + 2 < T_) {                          // reload pfB for t+2
                const u16* pt = xwp + (size_t)(t + 2) * tstride;
#pragma unroll
                for (int tau = 0; tau < 4; ++tau) pfB[tau] = *(const uint2*)(pt + tau * 16);
            }
            const uint4* hb = (const uint4*)&hbuf[cur][0];
#pragma unroll
            for (int kap = 0; kap < 8; ++kap) {
                U16x8Cast c; c.v = hb[kap * 64 + lane];
#pragma unroll
                for (int tau = 0; tau < 4; ++tau)
                    acc[tau] = __builtin_amdgcn_mfma_f32_16x16x32_bf16(wf[tau][kap], c.b, acc[tau], 0, 0, 0);
            }
            if (t != T_ - 1) {                         // last h feeds fc only
                u16* wb = &hbuf[cur ^ 1][0];
#pragma unroll
                for (int tau = 0; tau < 4; ++tau) {
                    uint2 pk = pack4(tanh_pre(acc[tau][0]), tanh_pre(acc[tau][1]),
                                     tanh_pre(acc[tau][2]), tanh_pre(acc[tau][3]));
                    *(uint2*)(wb + widx[tau]) = pk;
                }
                WG_BARRIER();
                cur ^= 1;
            }
        }
    }

    // fc head: out[b] = sum_n tanh(h)[n] * fc_w[n] + fc_b
    float4 fcw[4];
#pragma unroll
    for (int tau = 0; tau < 4; ++tau)
        fcw[tau] = *(const float4*)(fc_w + wave * 64 + tau * 16 + q * 4);

    float partial = 0.f;
#pragma unroll
    for (int tau = 0; tau < 4; ++tau) {
        partial += tanh_pre(acc[tau][0]) * fcw[tau].x;
        partial += tanh_pre(acc[tau][1]) * fcw[tau].y;
        partial += tanh_pre(acc[tau][2]) * fcw[tau].z;
        partial += tanh_pre(acc[tau][3]) * fcw[tau].w;
    }
    partial += __shfl_xor(partial, 16);
    partial += __shfl_xor(partial, 32);
    if (lane < 16) red[wave][m] = partial;
    __syncthreads();
    if (tid < 16) {
        float s = red[0][tid] + red[1][tid] + red[2][tid] + red[3][tid];
        out[b0 + tid] = s + fc_b[0];
    }
}

// =====================================================================
extern "C" void kernel_launch(void* const* d_in, const int* in_sizes, int n_in,
                              void* d_out, int out_size, void* d_ws, size_t ws_size,
                              hipStream_t stream) {
    const float* x    = (const float*)d_in[0];
    const float* W_ih = (const float*)d_in[1];
    const float* W_hh = (const float*)d_in[2];
    const float* b_ih = (const float*)d_in[3];
    const float* b_hh = (const float*)d_in[4];
    const float* fc_w = (const float*)d_in[5];
    const float* fc_b = (const float*)d_in[6];
    float* out = (float*)d_out;

    u16* xwbuf = (u16*)d_ws;                           // 64 MB bf16 [T][B][H]
    xw_gemm_mfma<<<(B_ * T_) / 128, 256, 0, stream>>>(x, W_ih, b_ih, b_hh, xwbuf);
    rnn_scan_mfma<<<B_ / 16, 256, 0, stream>>>(xwbuf, W_hh, fc_w, fc_b, out);
}

// Round 7
// 371.302 us; speedup vs baseline: 1.2187x; 1.2187x over previous
//
#include <hip/hip_runtime.h>
#include <hip/hip_bf16.h>

#define B_ 256
#define T_ 512
#define I_ 128
#define H_ 256

typedef __bf16 bf16x8 __attribute__((ext_vector_type(8)));
typedef float  f32x4  __attribute__((ext_vector_type(4)));
typedef unsigned short u16;
typedef unsigned int   u32;

union U16x8Cast { uint4 v; bf16x8 b; };

__device__ inline u16 f2b(float f) {           // fp32 -> bf16 bits (RNE)
    union { __bf16 h; u16 u; } c; c.h = (__bf16)f; return c.u;
}
__device__ inline bf16x8 pack8(float4 lo, float4 hi) {
    bf16x8 f;
    f[0]=(__bf16)lo.x; f[1]=(__bf16)lo.y; f[2]=(__bf16)lo.z; f[3]=(__bf16)lo.w;
    f[4]=(__bf16)hi.x; f[5]=(__bf16)hi.y; f[6]=(__bf16)hi.z; f[7]=(__bf16)hi.w;
    return f;
}
__device__ inline uint2 pack4(float a, float b, float c, float d) {
    uint2 p;
    p.x = (u32)f2b(a) | ((u32)f2b(b) << 16);
    p.y = (u32)f2b(c) | ((u32)f2b(d) << 16);
    return p;
}
__device__ inline f32x4 b4_to_f32x4(uint2 u) {
    f32x4 r;
    r[0] = __uint_as_float(u.x << 16);
    r[1] = __uint_as_float(u.x & 0xFFFF0000u);
    r[2] = __uint_as_float(u.y << 16);
    r[3] = __uint_as_float(u.y & 0xFFFF0000u);
    return r;
}
// tanh(x) = 1 - 2/(1+e^{2x}); v_rcp (±1 ulp) instead of the ~10-instr
// precise-div sequence the compiler emits for 1.f/x without fast-math.
__device__ inline float fast_tanh(float x) {
    float e = __expf(2.f * x);                 // v_mul + v_exp
    float d = 1.f + e;
    float r;
    asm("v_rcp_f32 %0, %1" : "=v"(r) : "v"(d));
    return fmaf(-2.f, r, 1.f);                 // x<<0 -> -1, x>>0 -> 1, no NaN
}

// LDS-drain-only workgroup barrier: does NOT wait vmcnt, so global
// prefetch loads stay in flight across the barrier (the __syncthreads
// vmcnt(0) drain was the ~900-cyc/step exposed-HBM-latency stall).
#define WG_BARRIER() asm volatile("s_waitcnt lgkmcnt(0)\n\ts_barrier" ::: "memory")

// =====================================================================
// Kernel 1 (MFMA GEMM, R5 version): xw[t][b][n] = x[bT+t,:]*W_ih[n,:]+bias
// 128-row m-tile, LDS-staged coalesced bf16 stores to [t][b][n].
// =====================================================================
#define LDST 264
__global__ __launch_bounds__(256, 2) void xw_gemm_mfma(const float* __restrict__ x,
                                                       const float* __restrict__ W_ih,
                                                       const float* __restrict__ b_ih,
                                                       const float* __restrict__ b_hh,
                                                       u16* __restrict__ xw) {
    __shared__ u16 tile[64 * LDST];

    const int tid  = (int)threadIdx.x;
    const int wave = tid >> 6;
    const int lane = tid & 63;
    const int q    = lane >> 4;
    const int ml   = lane & 15;
    const int m0   = (int)blockIdx.x * 128;
    const int b    = m0 >> 9;
    const int t0   = m0 & 511;
    const int n0   = wave * 64;

    bf16x8 wA[4][4];
#pragma unroll
    for (int tau = 0; tau < 4; ++tau) {
        const float* wr = W_ih + (size_t)(n0 + tau * 16 + ml) * I_;
#pragma unroll
        for (int kap = 0; kap < 4; ++kap) {
            const int k0 = kap * 32 + q * 8;
            wA[tau][kap] = pack8(*(const float4*)(wr + k0), *(const float4*)(wr + k0 + 4));
        }
    }

    f32x4 acc[8][4];
#pragma unroll
    for (int mt = 0; mt < 8; ++mt)
#pragma unroll
        for (int tau = 0; tau < 4; ++tau) acc[mt][tau] = (f32x4)0.f;

#pragma unroll
    for (int kap = 0; kap < 4; ++kap) {
        bf16x8 xB[8];
#pragma unroll
        for (int mt = 0; mt < 8; ++mt) {
            const float* xr = x + (size_t)(m0 + mt * 16 + ml) * I_ + kap * 32 + q * 8;
            xB[mt] = pack8(*(const float4*)xr, *(const float4*)(xr + 4));
        }
#pragma unroll
        for (int mt = 0; mt < 8; ++mt)
#pragma unroll
            for (int tau = 0; tau < 4; ++tau)
                acc[mt][tau] = __builtin_amdgcn_mfma_f32_16x16x32_bf16(
                    wA[tau][kap], xB[mt], acc[mt][tau], 0, 0, 0);
    }

    float4 bias4[4];
#pragma unroll
    for (int tau = 0; tau < 4; ++tau) {
        const int n = n0 + tau * 16 + q * 4;
        float4 bi = *(const float4*)(b_ih + n);
        float4 bh = *(const float4*)(b_hh + n);
        bias4[tau] = make_float4(bi.x + bh.x, bi.y + bh.y, bi.z + bh.z, bi.w + bh.w);
    }

#pragma unroll
    for (int p = 0; p < 2; ++p) {
        if (p) __syncthreads();
#pragma unroll
        for (int mt = 0; mt < 4; ++mt) {
            const int row = mt * 16 + ml;
            const int mg  = p * 4 + mt;
#pragma unroll
            for (int tau = 0; tau < 4; ++tau) {
                uint2 pk = pack4(acc[mg][tau][0] + bias4[tau].x,
                                 acc[mg][tau][1] + bias4[tau].y,
                                 acc[mg][tau][2] + bias4[tau].z,
                                 acc[mg][tau][3] + bias4[tau].w);
                *(uint2*)(tile + row * LDST + n0 + tau * 16 + q * 4) = pk;
            }
        }
        __syncthreads();
#pragma unroll
        for (int s = 0; s < 4; ++s) {
            const int rr = s * 16 + (tid >> 4);
            const int c  = tid & 15;
            const uint4* srcp = (const uint4*)(tile + rr * LDST);
            uint4* dstp = (uint4*)(xw + ((size_t)(t0 + p * 64 + rr) * B_ + b) * H_);
            uint4 v0 = srcp[c];
            uint4 v1 = srcp[c + 16];
            dstp[c] = v0;
            dstp[c + 16] = v1;
        }
    }
}

// =====================================================================
// Kernel 2 (MFMA scan) — R4 structure (best measured) + three fixes:
//  1. lgkm-only barrier (no vmcnt drain of the xw prefetch)
//  2. t-loop unrolled x2 with ALTERNATING prefetch regs pfA/pfB (no
//     register copies -> true 2-step issue-to-use distance, HBM hidden)
//  3. v_rcp-based tanh (kills precise-div sequence)
// 16 WGs x 512 thr (8 waves, 2/SIMD). Wave owns 32 H-rows as inline-packed
// A-frags. h ping-pongs in LDS in B-frag order (linear b128, conflict-free).
// =====================================================================
__global__ __launch_bounds__(512, 2) void rnn_scan_mfma(const u16* __restrict__ xw,
                                                        const float* __restrict__ W_hh,
                                                        const float* __restrict__ fc_w,
                                                        const float* __restrict__ fc_b,
                                                        float* __restrict__ out) {
    __shared__ __attribute__((aligned(16))) u16 hbuf[2][4096];  // 2 x 8 KB
    __shared__ float red[8][16];

    const int tid  = (int)threadIdx.x;
    const int wave = tid >> 6;          // 0..7
    const int lane = tid & 63;
    const int q    = lane >> 4;
    const int m    = lane & 15;
    const int b0   = (int)blockIdx.x * 16;

    // W_hh A-frags: lane holds W_hh[n = wave*32+tau2*16+m][k = kap*32+q*8+0..7]
    bf16x8 wf[2][8];
#pragma unroll
    for (int tau2 = 0; tau2 < 2; ++tau2) {
        const float* wr = W_hh + (size_t)(wave * 32 + tau2 * 16 + m) * H_;
#pragma unroll
        for (int kap = 0; kap < 8; ++kap) {
            const int k0 = kap * 32 + q * 8;
            wf[tau2][kap] = pack8(*(const float4*)(wr + k0), *(const float4*)(wr + k0 + 4));
        }
    }

    // LDS write indices (u16 units) for C -> B-frag relayout
    int widx[2];
#pragma unroll
    for (int tau2 = 0; tau2 < 2; ++tau2) {
        const int nbw = wave * 32 + tau2 * 16 + q * 4;
        widx[tau2] = (nbw >> 5) * 512 + (((nbw >> 3) & 3) * 16 + m) * 8 + (nbw & 7);
    }

    {   // zero h buffer 0 (8 KB = 512 uint4)
        uint4* p = (uint4*)&hbuf[0][0];
        const uint4 z = {0u, 0u, 0u, 0u};
        p[tid] = z;
    }
    WG_BARRIER();

    // xw ([t][b][n]): lane reads 2 x uint2 per step.
    const u16* xwp = xw + (size_t)(b0 + m) * H_ + (wave * 32 + q * 4);
    const size_t tstride = (size_t)B_ * H_;

    uint2 pfA[2], pfB[2];                              // alternating, never copied
    pfA[0] = *(const uint2*)(xwp);
    pfA[1] = *(const uint2*)(xwp + 16);
    pfB[0] = *(const uint2*)(xwp + tstride);
    pfB[1] = *(const uint2*)(xwp + tstride + 16);

    int cur = 0;
    f32x4 acc[2];
    for (int tt = 0; tt < T_ / 2; ++tt) {
        // ---------- step A: t = 2*tt (even, never last) ----------
        {
            const int t = 2 * tt;
            acc[0] = b4_to_f32x4(pfA[0]);
            acc[1] = b4_to_f32x4(pfA[1]);
            if (t + 2 < T_) {                          // reload pfA for t+2
                const u16* pt = xwp + (size_t)(t + 2) * tstride;
                pfA[0] = *(const uint2*)(pt);
                pfA[1] = *(const uint2*)(pt + 16);
            }
            const uint4* hb = (const uint4*)&hbuf[cur][0];
#pragma unroll
            for (int kap = 0; kap < 8; ++kap) {
                U16x8Cast c; c.v = hb[kap * 64 + lane];
                acc[0] = __builtin_amdgcn_mfma_f32_16x16x32_bf16(wf[0][kap], c.b, acc[0], 0, 0, 0);
                acc[1] = __builtin_amdgcn_mfma_f32_16x16x32_bf16(wf[1][kap], c.b, acc[1], 0, 0, 0);
            }
            u16* wb = &hbuf[cur ^ 1][0];
#pragma unroll
            for (int tau2 = 0; tau2 < 2; ++tau2) {
                uint2 pk = pack4(fast_tanh(acc[tau2][0]), fast_tanh(acc[tau2][1]),
                                 fast_tanh(acc[tau2][2]), fast_tanh(acc[tau2][3]));
                *(uint2*)(wb + widx[tau2]) = pk;
            }
            WG_BARRIER();
            cur ^= 1;
        }
        // ---------- step B: t = 2*tt+1 (t = T_-1 on the last iter) ----------
        {
            const int t = 2 * tt + 1;
            acc[0] = b4_to_f32x4(pfB[0]);
            acc[1] = b4_to_f32x4(pfB[1]);
            if (t + 2 < T_) {                          // reload pfB for t+2
                const u16* pt = xwp + (size_t)(t + 2) * tstride;
                pfB[0] = *(const uint2*)(pt);
                pfB[1] = *(const uint2*)(pt + 16);
            }
            const uint4* hb = (const uint4*)&hbuf[cur][0];
#pragma unroll
            for (int kap = 0; kap < 8; ++kap) {
                U16x8Cast c; c.v = hb[kap * 64 + lane];
                acc[0] = __builtin_amdgcn_mfma_f32_16x16x32_bf16(wf[0][kap], c.b, acc[0], 0, 0, 0);
                acc[1] = __builtin_amdgcn_mfma_f32_16x16x32_bf16(wf[1][kap], c.b, acc[1], 0, 0, 0);
            }
            if (t != T_ - 1) {                         // last h feeds fc only
                u16* wb = &hbuf[cur ^ 1][0];
#pragma unroll
                for (int tau2 = 0; tau2 < 2; ++tau2) {
                    uint2 pk = pack4(fast_tanh(acc[tau2][0]), fast_tanh(acc[tau2][1]),
                                     fast_tanh(acc[tau2][2]), fast_tanh(acc[tau2][3]));
                    *(uint2*)(wb + widx[tau2]) = pk;
                }
                WG_BARRIER();
                cur ^= 1;
            }
        }
    }

    // fc head: out[b] = sum_n tanh(h)[n] * fc_w[n] + fc_b
    float4 fcw[2];
#pragma unroll
    for (int tau2 = 0; tau2 < 2; ++tau2)
        fcw[tau2] = *(const float4*)(fc_w + wave * 32 + tau2 * 16 + q * 4);

    float partial = 0.f;
#pragma unroll
    for (int tau2 = 0; tau2 < 2; ++tau2) {
        partial += fast_tanh(acc[tau2][0]) * fcw[tau2].x;
        partial += fast_tanh(acc[tau2][1]) * fcw[tau2].y;
        partial += fast_tanh(acc[tau2][2]) * fcw[tau2].z;
        partial += fast_tanh(acc[tau2][3]) * fcw[tau2].w;
    }
    partial += __shfl_xor(partial, 16);
    partial += __shfl_xor(partial, 32);
    __syncthreads();
    if (lane < 16) red[wave][m] = partial;
    __syncthreads();
    if (tid < 16) {
        float s = red[0][tid] + red[1][tid] + red[2][tid] + red[3][tid]
                + red[4][tid] + red[5][tid] + red[6][tid] + red[7][tid];
        out[b0 + tid] = s + fc_b[0];
    }
}

// =====================================================================
extern "C" void kernel_launch(void* const* d_in, const int* in_sizes, int n_in,
                              void* d_out, int out_size, void* d_ws, size_t ws_size,
                              hipStream_t stream) {
    const float* x    = (const float*)d_in[0];
    const float* W_ih = (const float*)d_in[1];
    const float* W_hh = (const float*)d_in[2];
    const float* b_ih = (const float*)d_in[3];
    const float* b_hh = (const float*)d_in[4];
    const float* fc_w = (const float*)d_in[5];
    const float* fc_b = (const float*)d_in[6];
    float* out = (float*)d_out;

    u16* xwbuf = (u16*)d_ws;                           // 64 MB bf16 [T][B][H]
    xw_gemm_mfma<<<(B_ * T_) / 128, 256, 0, stream>>>(x, W_ih, b_ih, b_hh, xwbuf);
    rnn_scan_mfma<<<B_ / 16, 512, 0, stream>>>(xwbuf, W_hh, fc_w, fc_b, out);
}

// Round 9
// 369.983 us; speedup vs baseline: 1.2230x; 1.0036x over previous
//
#include <hip/hip_runtime.h>
#include <hip/hip_bf16.h>

#define B_ 256
#define T_ 512
#define I_ 128
#define H_ 256

// 2*log2(e): W_ih, W_hh, bias pre-scaled so the scan accumulator holds
// s = 2*log2e*z and tanh(z) = 1 - 2/(1 + 2^s) needs no pre-multiply.
// Verified passing in R1 (absmax 0.0039). exp2/rcp via COMPILER BUILTINS,
// not inline asm: the hazard recognizer cannot see inside asm strings and
// a TRANS-op consumer scheduled immediately after stale-reads the result
// (the pinned R5 failure mechanism).
#define SC 2.885390081777927f

typedef __bf16 bf16x8 __attribute__((ext_vector_type(8)));
typedef float  f32x4  __attribute__((ext_vector_type(4)));
typedef unsigned short u16;
typedef unsigned int   u32;

union U16x8Cast { uint4 v; bf16x8 b; };

__device__ inline u16 f2b(float f) {           // fp32 -> bf16 bits (RNE)
    union { __bf16 h; u16 u; } c; c.h = (__bf16)f; return c.u;
}
__device__ inline bf16x8 pack8(float4 lo, float4 hi) {
    bf16x8 f;
    f[0]=(__bf16)lo.x; f[1]=(__bf16)lo.y; f[2]=(__bf16)lo.z; f[3]=(__bf16)lo.w;
    f[4]=(__bf16)hi.x; f[5]=(__bf16)hi.y; f[6]=(__bf16)hi.z; f[7]=(__bf16)hi.w;
    return f;
}
__device__ inline bf16x8 pack8s(float4 lo, float4 hi, float s) {
    bf16x8 f;
    f[0]=(__bf16)(lo.x*s); f[1]=(__bf16)(lo.y*s); f[2]=(__bf16)(lo.z*s); f[3]=(__bf16)(lo.w*s);
    f[4]=(__bf16)(hi.x*s); f[5]=(__bf16)(hi.y*s); f[6]=(__bf16)(hi.z*s); f[7]=(__bf16)(hi.w*s);
    return f;
}
__device__ inline uint2 pack4(float a, float b, float c, float d) {
    uint2 p;
    p.x = (u32)f2b(a) | ((u32)f2b(b) << 16);
    p.y = (u32)f2b(c) | ((u32)f2b(d) << 16);
    return p;
}
__device__ inline f32x4 b4_to_f32x4(uint2 u) {
    f32x4 r;
    r[0] = __uint_as_float(u.x << 16);
    r[1] = __uint_as_float(u.x & 0xFFFF0000u);
    r[2] = __uint_as_float(u.y << 16);
    r[3] = __uint_as_float(u.y & 0xFFFF0000u);
    return r;
}
// tanh from pre-scaled s = 2*log2e*z: tanh(z) = 1 - 2/(1 + 2^s).
// Builtins only — compiler owns TRANS-op hazard handling.
// s -> +inf: e=inf, r=0 -> 1; s -> -inf: e=0, r=1 -> -1. No NaN.
__device__ inline float tanh_pre(float s) {
    float e = __builtin_amdgcn_exp2f(s);
    float r = __builtin_amdgcn_rcpf(1.f + e);
    return fmaf(-2.f, r, 1.f);
}

// LDS-drain-only workgroup barrier: does NOT wait vmcnt, so global
// prefetch loads stay in flight across the barrier. (R0-verified)
#define WG_BARRIER() asm volatile("s_waitcnt lgkmcnt(0)\n\ts_barrier" ::: "memory")

// =====================================================================
// Kernel 1 (MFMA GEMM): xw[t][b][n] = SC * (x[bT+t,:]*W_ih[n,:] + bias)
// VERBATIM the R1 version (passed, absmax 0.0039).
// =====================================================================
#define LDST 264
__global__ __launch_bounds__(256, 2) void xw_gemm_mfma(const float* __restrict__ x,
                                                       const float* __restrict__ W_ih,
                                                       const float* __restrict__ b_ih,
                                                       const float* __restrict__ b_hh,
                                                       u16* __restrict__ xw) {
    __shared__ u16 tile[64 * LDST];

    const int tid  = (int)threadIdx.x;
    const int wave = tid >> 6;
    const int lane = tid & 63;
    const int q    = lane >> 4;
    const int ml   = lane & 15;
    const int m0   = (int)blockIdx.x * 128;
    const int b    = m0 >> 9;
    const int t0   = m0 & 511;
    const int n0   = wave * 64;

    bf16x8 wA[4][4];
#pragma unroll
    for (int tau = 0; tau < 4; ++tau) {
        const float* wr = W_ih + (size_t)(n0 + tau * 16 + ml) * I_;
#pragma unroll
        for (int kap = 0; kap < 4; ++kap) {
            const int k0 = kap * 32 + q * 8;
            wA[tau][kap] = pack8s(*(const float4*)(wr + k0), *(const float4*)(wr + k0 + 4), SC);
        }
    }

    f32x4 acc[8][4];
#pragma unroll
    for (int mt = 0; mt < 8; ++mt)
#pragma unroll
        for (int tau = 0; tau < 4; ++tau) acc[mt][tau] = (f32x4)0.f;

#pragma unroll
    for (int kap = 0; kap < 4; ++kap) {
        bf16x8 xB[8];
#pragma unroll
        for (int mt = 0; mt < 8; ++mt) {
            const float* xr = x + (size_t)(m0 + mt * 16 + ml) * I_ + kap * 32 + q * 8;
            xB[mt] = pack8(*(const float4*)xr, *(const float4*)(xr + 4));
        }
#pragma unroll
        for (int mt = 0; mt < 8; ++mt)
#pragma unroll
            for (int tau = 0; tau < 4; ++tau)
                acc[mt][tau] = __builtin_amdgcn_mfma_f32_16x16x32_bf16(
                    wA[tau][kap], xB[mt], acc[mt][tau], 0, 0, 0);
    }

    float4 bias4[4];
#pragma unroll
    for (int tau = 0; tau < 4; ++tau) {
        const int n = n0 + tau * 16 + q * 4;
        float4 bi = *(const float4*)(b_ih + n);
        float4 bh = *(const float4*)(b_hh + n);
        bias4[tau] = make_float4((bi.x + bh.x) * SC, (bi.y + bh.y) * SC,
                                 (bi.z + bh.z) * SC, (bi.w + bh.w) * SC);
    }

#pragma unroll
    for (int p = 0; p < 2; ++p) {
        if (p) __syncthreads();
#pragma unroll
        for (int mt = 0; mt < 4; ++mt) {
            const int row = mt * 16 + ml;
            const int mg  = p * 4 + mt;
#pragma unroll
            for (int tau = 0; tau < 4; ++tau) {
                uint2 pk = pack4(acc[mg][tau][0] + bias4[tau].x,
                                 acc[mg][tau][1] + bias4[tau].y,
                                 acc[mg][tau][2] + bias4[tau].z,
                                 acc[mg][tau][3] + bias4[tau].w);
                *(uint2*)(tile + row * LDST + n0 + tau * 16 + q * 4) = pk;
            }
        }
        __syncthreads();
#pragma unroll
        for (int s = 0; s < 4; ++s) {
            const int rr = s * 16 + (tid >> 4);
            const int c  = tid & 15;
            const uint4* srcp = (const uint4*)(tile + rr * LDST);
            uint4* dstp = (uint4*)(xw + ((size_t)(t0 + p * 64 + rr) * B_ + b) * H_);
            uint4 v0 = srcp[c];
            uint4 v1 = srcp[c + 16];
            dstp[c] = v0;
            dstp[c + 16] = v1;
        }
    }
}

// =====================================================================
// Kernel 2 (MFMA scan) — byte-identical to the R7-re-verified R0
// structure (8 waves / launch_bounds(512,2) / double-buffered h / uniform
// WG_BARRIER / pfA-pfB alternating prefetch). Exactly two value-level
// substitutions: wf loaded with pack8s(SC); tanh via builtin tanh_pre.
// =====================================================================
__global__ __launch_bounds__(512, 2) void rnn_scan_mfma(const u16* __restrict__ xw,
                                                        const float* __restrict__ W_hh,
                                                        const float* __restrict__ fc_w,
                                                        const float* __restrict__ fc_b,
                                                        float* __restrict__ out) {
    __shared__ __attribute__((aligned(16))) u16 hbuf[2][4096];  // 2 x 8 KB
    __shared__ float red[8][16];

    const int tid  = (int)threadIdx.x;
    const int wave = tid >> 6;          // 0..7
    const int lane = tid & 63;
    const int q    = lane >> 4;
    const int m    = lane & 15;
    const int b0   = (int)blockIdx.x * 16;

    // W_hh A-frags (SC-scaled): lane holds SC*W_hh[wave*32+tau2*16+m][kap*32+q*8+0..7]
    bf16x8 wf[2][8];
#pragma unroll
    for (int tau2 = 0; tau2 < 2; ++tau2) {
        const float* wr = W_hh + (size_t)(wave * 32 + tau2 * 16 + m) * H_;
#pragma unroll
        for (int kap = 0; kap < 8; ++kap) {
            const int k0 = kap * 32 + q * 8;
            wf[tau2][kap] = pack8s(*(const float4*)(wr + k0), *(const float4*)(wr + k0 + 4), SC);
        }
    }

    // LDS write indices (u16 units) for C -> B-frag relayout
    int widx[2];
#pragma unroll
    for (int tau2 = 0; tau2 < 2; ++tau2) {
        const int nbw = wave * 32 + tau2 * 16 + q * 4;
        widx[tau2] = (nbw >> 5) * 512 + (((nbw >> 3) & 3) * 16 + m) * 8 + (nbw & 7);
    }

    {   // zero h buffer 0 (8 KB = 512 uint4)
        uint4* p = (uint4*)&hbuf[0][0];
        const uint4 z = {0u, 0u, 0u, 0u};
        p[tid] = z;
    }
    WG_BARRIER();

    // xw ([t][b][n]): lane reads 2 x uint2 per step.
    const u16* xwp = xw + (size_t)(b0 + m) * H_ + (wave * 32 + q * 4);
    const size_t tstride = (size_t)B_ * H_;

    uint2 pfA[2], pfB[2];                              // alternating, never copied
    pfA[0] = *(const uint2*)(xwp);
    pfA[1] = *(const uint2*)(xwp + 16);
    pfB[0] = *(const uint2*)(xwp + tstride);
    pfB[1] = *(const uint2*)(xwp + tstride + 16);

    int cur = 0;
    f32x4 acc[2];
    for (int tt = 0; tt < T_ / 2; ++tt) {
        // ---------- step A: t = 2*tt (even, never last) ----------
        {
            const int t = 2 * tt;
            acc[0] = b4_to_f32x4(pfA[0]);
            acc[1] = b4_to_f32x4(pfA[1]);
            if (t + 2 < T_) {                          // reload pfA for t+2
                const u16* pt = xwp + (size_t)(t + 2) * tstride;
                pfA[0] = *(const uint2*)(pt);
                pfA[1] = *(const uint2*)(pt + 16);
            }
            const uint4* hb = (const uint4*)&hbuf[cur][0];
#pragma unroll
            for (int kap = 0; kap < 8; ++kap) {
                U16x8Cast c; c.v = hb[kap * 64 + lane];
                acc[0] = __builtin_amdgcn_mfma_f32_16x16x32_bf16(wf[0][kap], c.b, acc[0], 0, 0, 0);
                acc[1] = __builtin_amdgcn_mfma_f32_16x16x32_bf16(wf[1][kap], c.b, acc[1], 0, 0, 0);
            }
            u16* wb = &hbuf[cur ^ 1][0];
#pragma unroll
            for (int tau2 = 0; tau2 < 2; ++tau2) {
                uint2 pk = pack4(tanh_pre(acc[tau2][0]), tanh_pre(acc[tau2][1]),
                                 tanh_pre(acc[tau2][2]), tanh_pre(acc[tau2][3]));
                *(uint2*)(wb + widx[tau2]) = pk;
            }
            WG_BARRIER();
            cur ^= 1;
        }
        // ---------- step B: t = 2*tt+1 (t = T_-1 on the last iter) ----------
        {
            const int t = 2 * tt + 1;
            acc[0] = b4_to_f32x4(pfB[0]);
            acc[1] = b4_to_f32x4(pfB[1]);
            if (t + 2 < T_) {                          // reload pfB for t+2
                const u16* pt = xwp + (size_t)(t + 2) * tstride;
                pfB[0] = *(const uint2*)(pt);
                pfB[1] = *(const uint2*)(pt + 16);
            }
            const uint4* hb = (const uint4*)&hbuf[cur][0];
#pragma unroll
            for (int kap = 0; kap < 8; ++kap) {
                U16x8Cast c; c.v = hb[kap * 64 + lane];
                acc[0] = __builtin_amdgcn_mfma_f32_16x16x32_bf16(wf[0][kap], c.b, acc[0], 0, 0, 0);
                acc[1] = __builtin_amdgcn_mfma_f32_16x16x32_bf16(wf[1][kap], c.b, acc[1], 0, 0, 0);
            }
            if (t != T_ - 1) {                         // last h feeds fc only
                u16* wb = &hbuf[cur ^ 1][0];
#pragma unroll
                for (int tau2 = 0; tau2 < 2; ++tau2) {
                    uint2 pk = pack4(tanh_pre(acc[tau2][0]), tanh_pre(acc[tau2][1]),
                                     tanh_pre(acc[tau2][2]), tanh_pre(acc[tau2][3]));
                    *(uint2*)(wb + widx[tau2]) = pk;
                }
                WG_BARRIER();
                cur ^= 1;
            }
        }
    }

    // fc head: out[b] = sum_n tanh(h)[n] * fc_w[n] + fc_b
    float4 fcw[2];
#pragma unroll
    for (int tau2 = 0; tau2 < 2; ++tau2)
        fcw[tau2] = *(const float4*)(fc_w + wave * 32 + tau2 * 16 + q * 4);

    float partial = 0.f;
#pragma unroll
    for (int tau2 = 0; tau2 < 2; ++tau2) {
        partial += tanh_pre(acc[tau2][0]) * fcw[tau2].x;
        partial += tanh_pre(acc[tau2][1]) * fcw[tau2].y;
        partial += tanh_pre(acc[tau2][2]) * fcw[tau2].z;
        partial += tanh_pre(acc[tau2][3]) * fcw[tau2].w;
    }
    partial += __shfl_xor(partial, 16);
    partial += __shfl_xor(partial, 32);
    __syncthreads();
    if (lane < 16) red[wave][m] = partial;
    __syncthreads();
    if (tid < 16) {
        float s = red[0][tid] + red[1][tid] + red[2][tid] + red[3][tid]
                + red[4][tid] + red[5][tid] + red[6][tid] + red[7][tid];
        out[b0 + tid] = s + fc_b[0];
    }
}

// =====================================================================
extern "C" void kernel_launch(void* const* d_in, const int* in_sizes, int n_in,
                              void* d_out, int out_size, void* d_ws, size_t ws_size,
                              hipStream_t stream) {
    const float* x    = (const float*)d_in[0];
    const float* W_ih = (const float*)d_in[1];
    const float* W_hh = (const float*)d_in[2];
    const float* b_ih = (const float*)d_in[3];
    const float* b_hh = (const float*)d_in[4];
    const float* fc_w = (const float*)d_in[5];
    const float* fc_b = (const float*)d_in[6];
    float* out = (float*)d_out;

    u16* xwbuf = (u16*)d_ws;                           // 64 MB bf16 [T][B][H]
    xw_gemm_mfma<<<(B_ * T_) / 128, 256, 0, stream>>>(x, W_ih, b_ih, b_hh, xwbuf);
    rnn_scan_mfma<<<B_ / 16, 512, 0, stream>>>(xwbuf, W_hh, fc_w, fc_b, out);
}